// Round 3
// baseline (139.731 us; speedup 1.0000x reference)
//
#include <hip/hip_runtime.h>
#include <hip/hip_bf16.h>

#define B_    8
#define N_    2048
#define FIN_  256
#define FOUT_ 128
#define NROWS (B_*N_)

typedef __attribute__((ext_vector_type(8))) short short8;
typedef __attribute__((ext_vector_type(4))) float f32x4;

__device__ __forceinline__ float bf2f(unsigned short u) {
  return __uint_as_float(((unsigned int)u) << 16);
}
__device__ __forceinline__ unsigned short f2bf(float f) {
  unsigned int u = __float_as_uint(f);
  u += 0x7FFFu + ((u >> 16) & 1u);   // RNE
  return (unsigned short)(u >> 16);
}
__device__ __forceinline__ float ldin(const void* p, size_t idx, int isbf) {
  if (isbf) return bf2f(((const unsigned short*)p)[idx]);
  return ((const float*)p)[idx];
}
__device__ __forceinline__ unsigned pk2bf(float a, float b) {
  return (unsigned)f2bf(a) | ((unsigned)f2bf(b) << 16);   // low = a (RNE)
}
// native exp2 (single v_exp_f32); fallback keeps exact same math via e^(x*ln2)
__device__ __forceinline__ float ex2(float x) {
#if __has_builtin(__builtin_amdgcn_exp2f)
  return __builtin_amdgcn_exp2f(x);
#else
  return __expf(x * 0.69314718056f);
#endif
}
// monotone float<->uint encoding for atomicMax float-max (all finite enc > 0)
__device__ __forceinline__ unsigned encf(float f) {
  unsigned u = __float_as_uint(f);
  return (u & 0x80000000u) ? ~u : (u | 0x80000000u);
}
__device__ __forceinline__ float decf(unsigned k) {
  return (k & 0x80000000u) ? __uint_as_float(k ^ 0x80000000u) : __uint_as_float(~k);
}
// per-block dtype self-detect (deterministic across blocks)
__device__ __forceinline__ int detect_bf(const void* x, int* cnt) {
  const unsigned short* u = (const unsigned short*)x;
  int c = 0;
  for (int i = threadIdx.x; i < 8192; i += 256) {
    unsigned short v = u[i];
    int e = (v >> 7) & 0xFF;
    if ((e >= 110 && e <= 145) || (v & 0x7FFF) == 0) c++;
  }
  cnt[threadIdx.x] = c;
  __syncthreads();
  for (int s = 128; s > 0; s >>= 1) {
    if (threadIdx.x < s) cnt[threadIdx.x] += cnt[threadIdx.x + s];
    __syncthreads();
  }
  return cnt[0] > 7373;   // 0.9 * 8192
}

// ---------- kernel 0: self-detect; blocks 0..127: WT; block 128: wa, flag,
//            MdstE init ----------
__global__ __launch_bounds__(256)
void k_prep(const void* __restrict__ x, const void* __restrict__ W,
            const void* __restrict__ a,
            unsigned short* __restrict__ WT, float* __restrict__ wa,
            int* __restrict__ flag, unsigned* __restrict__ MdstE) {
  __shared__ int cnt[256];
  const int isbf = detect_bf(x, cnt);
  if (blockIdx.x < 128) {
    int f = blockIdx.x, k = threadIdx.x;
    WT[f * 256 + k] = f2bf(ldin(W, (size_t)k * 128 + f, isbf));
  } else {
    __shared__ float as_s[256];
    int k = threadIdx.x;
    as_s[k] = ldin(a, k, isbf);
    __syncthreads();
    float s = 0.f, d = 0.f;
    for (int f = 0; f < 128; f++) {
      float w = ldin(W, (size_t)k * 128 + f, isbf);
      s += w * as_s[f];
      d += w * as_s[128 + f];
    }
    wa[k] = s;
    wa[256 + k] = d;
    if (k == 0) *flag = isbf;
    if (k < 8) MdstE[k * 32] = 0u;     // 0 < enc(f) for all finite f
  }
}

// ---------- kernel 1: h = x@W bf16 MFMA -> hT; fused fsrc/fdst = x@wa;
//            fused per-batch fdst max; cpack = (cx,cy,cz, fdst*log2e).
// hT 16B-half XOR swizzle on bit2 of f (phys_half = logical_half ^
// ((f>>2)&1)); k_attn reads with the matching hsel XOR. ----------
__global__ __launch_bounds__(256)
void k_h(const void* __restrict__ x, const void* __restrict__ coord,
         const unsigned short* __restrict__ WT,
         const float* __restrict__ wa, const int* __restrict__ flag,
         unsigned short* __restrict__ hT, float* __restrict__ fsrc,
         float4* __restrict__ cpack, unsigned* __restrict__ MdstE) {
  __shared__ __align__(16) unsigned short xs[32][264];
  __shared__ float wa_s[512];
  __shared__ float mxs[8];
  const int isbf = *flag;
  const int t    = threadIdx.x;
  const int row0 = blockIdx.x * 32;

  wa_s[t] = wa[t];
  wa_s[256 + t] = wa[256 + t];
  __syncthreads();

  const int c = t & 31;
  float sp[4], dp[4];
  if (isbf) {
    const unsigned short* xu = (const unsigned short*)x;
#pragma unroll
    for (int u = 0; u < 4; u++) {
      int r = u * 8 + (t >> 5);
      short8 sh = *(const short8*)&xu[(size_t)(row0 + r) * FIN_ + c * 8];
      *(short8*)&xs[r][c * 8] = sh;
      float s = 0.f, d = 0.f;
#pragma unroll
      for (int e = 0; e < 8; e++) {
        float xv = bf2f((unsigned short)sh[e]);
        s += xv * wa_s[c * 8 + e];
        d += xv * wa_s[256 + c * 8 + e];
      }
      sp[u] = s; dp[u] = d;
    }
  } else {
    const float* xf = (const float*)x;
#pragma unroll
    for (int u = 0; u < 4; u++) {
      int r = u * 8 + (t >> 5);
      float4 v0 = *(const float4*)&xf[(size_t)(row0 + r) * FIN_ + c * 8];
      float4 v1 = *(const float4*)&xf[(size_t)(row0 + r) * FIN_ + c * 8 + 4];
      float vv[8] = {v0.x, v0.y, v0.z, v0.w, v1.x, v1.y, v1.z, v1.w};
      short8 sh;
      float s = 0.f, d = 0.f;
#pragma unroll
      for (int e = 0; e < 8; e++) {
        sh[e] = (short)f2bf(vv[e]);
        s += vv[e] * wa_s[c * 8 + e];
        d += vv[e] * wa_s[256 + c * 8 + e];
      }
      *(short8*)&xs[r][c * 8] = sh;
      sp[u] = s; dp[u] = d;
    }
  }
#pragma unroll
  for (int off = 16; off >= 1; off >>= 1) {
#pragma unroll
    for (int u = 0; u < 4; u++) {
      sp[u] += __shfl_xor(sp[u], off, 64);
      dp[u] += __shfl_xor(dp[u], off, 64);
    }
  }
  if (c == 0) {
    float lm = -1e30f;
#pragma unroll
    for (int u = 0; u < 4; u++) {
      int r = u * 8 + (t >> 5);
      size_t rg = (size_t)(row0 + r);
      fsrc[rg] = sp[u];
      cpack[rg] = make_float4(ldin(coord, rg * 3 + 0, isbf),
                              ldin(coord, rg * 3 + 1, isbf),
                              ldin(coord, rg * 3 + 2, isbf),
                              dp[u] * 1.44269504f);     // fdst pre-scaled by log2e
      lm = fmaxf(lm, dp[u]);
    }
    mxs[t >> 5] = lm;
  }
  __syncthreads();
  if (t == 0) {
    float m8 = mxs[0];
#pragma unroll
    for (int i = 1; i < 8; i++) m8 = fmaxf(m8, mxs[i]);
    atomicMax(&MdstE[(row0 >> 11) * 32], encf(m8));   // 64 atomics/line, padded
  }

  const int lane = t & 63, w = t >> 6;
  const int m = lane & 15, quad = lane >> 4;
  const int slab = w >> 1, fh = w & 1;

  f32x4 acc[4];
#pragma unroll
  for (int i = 0; i < 4; i++) acc[i] = (f32x4){0.f, 0.f, 0.f, 0.f};

#pragma unroll
  for (int ks = 0; ks < 8; ks++) {
    short8 ah = *(const short8*)&xs[slab * 16 + m][ks * 32 + quad * 8];
#pragma unroll
    for (int ft = 0; ft < 4; ft++) {
      int f = fh * 64 + ft * 16 + m;
      short8 bh = *(const short8*)&WT[(size_t)f * 256 + ks * 32 + quad * 8];
      acc[ft] = __builtin_amdgcn_mfma_f32_16x16x32_bf16(ah, bh, acc[ft], 0, 0, 0);
    }
  }

  size_t n0 = (size_t)blockIdx.x * 2 + slab;
  unsigned short* hblk = hT + n0 * (FOUT_ * 16);
#pragma unroll
  for (int ft = 0; ft < 4; ft++) {
    int f = fh * 64 + ft * 16 + m;
    int jo = (quad * 4) ^ (((f >> 2) & 1) << 3);   // bank-swizzled 16B half
    *(uint2*)&hblk[f * 16 + jo] = make_uint2(
        pk2bf(acc[ft][0], acc[ft][1]), pk2bf(acc[ft][2], acc[ft][3]));
  }
}

// ---------- kernel 2 (r20): 64-q blocks, REG-staged LDS B, 1 barrier/tile --
// r19 (glds-staged B) SIGABRT'd on-device; every index/fence audit passed,
// so the glds construct itself is the prime suspect. r20 keeps the exact
// r19 pipeline but stages B via registers: per 128-j tile the 32 KB panel =
// 4x uint4 global loads + 4 lane-contiguous ds_write per thread (512 thr).
// Loads issue at the TOP of iter t (tile t+1), ds_writes land at the BOTTOM
// just before the barrier -- the ~600-cyc logits+MFMA phase hides the HBM/L2
// latency (T14). One __syncthreads per tile publishes ldsB/phi/cjs.
// Grid 256 = 1 block/CU, 512 thr (8 waves = 4 q-groups x 2 f-groups).
// B VMEM per q drops 4x vs the 16-q-block r18 structure.
// LDS 103 KB: B dbuf 64 KB + phi 34 KB + cjs 4.5 KB (gfx950 allows 160 KB).
// Bank hygiene: B ds_reads 2-way-free (k_h hsel swizzle); phi rows 136
// shorts (272 B); cjs padded j+(j>>3); staging ds_writes lane-contiguous.
__global__ __launch_bounds__(512, 2)
void k_attn(const unsigned short* __restrict__ hT, const float4* __restrict__ cpack,
            const float* __restrict__ fsrc, const unsigned* __restrict__ MdstE,
            const int* __restrict__ flag, void* __restrict__ out) {
  const int isbf = *flag;
  const int tid = threadIdx.x;
  const int b   = blockIdx.x >> 5;
  const int q0  = (blockIdx.x & 31) * 64;

  __shared__ __align__(16) uint4 ldsBu[2][2048];            // 64 KB B panels
  __shared__ __align__(16) unsigned short phi[2][64][136];  // 34 KB
  __shared__ __align__(16) float4 cjs[2][144];              // 4.5 KB (padded)
  __shared__ float denomS[64];

  const int qA   = tid >> 3;              // 0..63: logit q row
  const int jseg = tid & 7;               // 16 j's: jseg*16 + 0..15
  const size_t qglb = (size_t)b * N_ + q0 + qA;
  const float4 cq  = cpack[qglb];
  const float  fsq = fsrc[qglb];
  const float  fsqL = fsq * 1.44269504f;
  const float  mBqL = -fmaxf(0.f, fsq + decf(MdstE[b * 32])) * 1.44269504f;

  const int lane = tid & 63, w = tid >> 6;
  const int m = lane & 15, quad = lane >> 4;
  const int qg = w & 3, fg = w >> 2;
  const int hsel = (quad & 1) ^ ((m >> 2) & 1);   // undo producer swizzle

  f32x4 acc[4], accD;
#pragma unroll
  for (int i = 0; i < 4; i++) acc[i] = (f32x4){0.f, 0.f, 0.f, 0.f};
  accD = (f32x4){0.f, 0.f, 0.f, 0.f};
  const short8 bones = {(short)0x3F80, (short)0x3F80, (short)0x3F80, (short)0x3F80,
                        (short)0x3F80, (short)0x3F80, (short)0x3F80, (short)0x3F80};

  const unsigned short* hTb = hT + (size_t)b * (N_ * FOUT_);
  const uint4* gB = (const uint4*)hTb;            // 2048 uint4 per 128-j tile
  const float4* cpb = cpack + (size_t)b * N_;

  // logits for tile tt -> 8 packed bf16 pairs (16 j's)
  auto logits = [&](int tt, unsigned* pk) {
    const float4* cb = cjs[tt & 1];
#pragma unroll
    for (int jp = 0; jp < 8; jp++) {
      const int j0 = jseg * 16 + 2 * jp;
      const int ix = j0 + (j0 >> 3);
      const float4 cj0 = cb[ix];
      const float4 cj1 = cb[ix + 1];
      float dx0 = cq.x - cj0.x, dy0 = cq.y - cj0.y, dz0 = cq.z - cj0.z;
      float dx1 = cq.x - cj1.x, dy1 = cq.y - cj1.y, dz1 = cq.z - cj1.z;
      float d20 = fmaf(dz0, dz0, fmaf(dy0, dy0, dx0 * dx0));
      float d21 = fmaf(dz1, dz1, fmaf(dy1, dy1, dx1 * dx1));
      float loc0 = ex2(-0.14426950408f * d20);       // = exp(-0.1*d2)
      float loc1 = ex2(-0.14426950408f * d21);
      float xL0 = fsqL + cj0.w, xL1 = fsqL + cj1.w;  // (fsq+fdst)*log2e
      float eL0 = fmaxf(xL0, 0.2f * xL0);            // leaky, scale-invariant
      float eL1 = fmaxf(xL1, 0.2f * xL1);
      float p0 = ex2(fmaf(eL0, loc0, mBqL));         // = exp(e*loc - Bq)
      float p1 = ex2(fmaf(eL1, loc1, mBqL));
      p0 = (d20 < 46.0517f) ? p0 : 0.f;
      p1 = (d21 < 46.0517f) ? p1 : 0.f;
      unsigned r;
      asm("v_cvt_pk_bf16_f32 %0, %1, %2" : "=v"(r) : "v"(p0), "v"(p1));
      pk[jp] = r;
    }
  };

  auto store_phi = [&](int tt, const unsigned* pk) {
    *(uint4*)&phi[tt & 1][qA][jseg * 16] =
        make_uint4(pk[0], pk[1], pk[2], pk[3]);
    *(uint4*)&phi[tt & 1][qA][jseg * 16 + 8] =
        make_uint4(pk[4], pk[5], pk[6], pk[7]);
  };

  auto mfma_tile = [&](int tb) {
    const unsigned short* pb = &phi[tb][qg * 16 + m][0];
    const unsigned short* bb = (const unsigned short*)ldsBu[tb];
#pragma unroll
    for (int ks = 0; ks < 4; ks++) {
      short8 ah = *(const short8*)&pb[ks * 32 + quad * 8];
      if (fg == 0)
        accD = __builtin_amdgcn_mfma_f32_16x16x32_bf16(ah, bones, accD, 0, 0, 0);
#pragma unroll
      for (int ft = 0; ft < 4; ft++) {
        const int f = fg * 64 + ft * 16 + m;
        const short8 bh = *(const short8*)
            &bb[(ks * 2 + (quad >> 1)) * 2048 + f * 16 + hsel * 8];
        acc[ft] = __builtin_amdgcn_mfma_f32_16x16x32_bf16(ah, bh, acc[ft], 0, 0, 0);
      }
    }
  };

  // ---- prologue: coords tiles 0,1; B panel 0 (reg-staged); logits(0) ----
  if (tid < 256) {
    const int tile = tid >> 7, j = tid & 127;
    cjs[tile][j + (j >> 3)] = cpb[tid];
  }
  {
    uint4 pv[4];
#pragma unroll
    for (int k = 0; k < 4; k++) pv[k] = gB[k * 512 + tid];
#pragma unroll
    for (int k = 0; k < 4; k++) ldsBu[0][k * 512 + tid] = pv[k];
  }
  __syncthreads();                         // cjs[0,1] + ldsB[0] ready
  {
    unsigned pk0[8];
    logits(0, pk0);
    store_phi(0, pk0);
  }
  __syncthreads();                         // phi[0] ready

  // ---- main loop: one barrier per 128-j tile ----
  const int jr = tid & 127;
  for (int t = 0; t < 16; t++) {
    // 1. issue next-tile loads (latency hides under logits+MFMA below)
    uint4 bv[4];
    if (t < 15) {
#pragma unroll
      for (int k = 0; k < 4; k++)
        bv[k] = gB[(size_t)(t + 1) * 2048 + k * 512 + tid];
    }
    float4 cg;
    if (t < 14 && tid < 128) cg = cpb[(t + 2) * 128 + jr];

    // 2. logits for tile t+1 (VALU-heavy; overlaps loads + MFMA)
    unsigned pk[8];
    if (t < 15) logits(t + 1, pk);         // reads cjs[(t+1)&1]

    // 3. MFMA for tile t
    mfma_tile(t & 1);                      // reads phi[t&1], ldsB[t&1]

    // 4. publish tile t+1 state (writes go to the OTHER buffers; prior
    //    reads of those buffers were fenced by the barrier at end of t-1)
    if (t < 15) {
#pragma unroll
      for (int k = 0; k < 4; k++)
        ldsBu[(t + 1) & 1][k * 512 + tid] = bv[k];
      store_phi(t + 1, pk);                // -> phi[(t+1)&1]
    }
    if (t < 14 && tid < 128) cjs[t & 1][jr + (jr >> 3)] = cg;  // tile t+2
    __syncthreads();
  }

  // ---- denominator share, normalize, elu, store ----
  if (fg == 0 && m == 0) {
#pragma unroll
    for (int r = 0; r < 4; r++) denomS[qg * 16 + quad * 4 + r] = accD[r];
  }
  __syncthreads();
#pragma unroll
  for (int ft = 0; ft < 4; ft++) {
    const int f = fg * 64 + ft * 16 + m;
#pragma unroll
    for (int r = 0; r < 4; r++) {
      const int q = qg * 16 + quad * 4 + r;
      float v = acc[ft][r] / fmaxf(denomS[q], 1e-30f);
      v = (v > 0.f) ? v : (__expf(v) - 1.0f);
      size_t oidx = ((size_t)(b * N_ + q0 + q)) * FOUT_ + f;
      if (isbf) ((unsigned short*)out)[oidx] = f2bf(v);
      else      ((float*)out)[oidx] = v;
    }
  }
}

extern "C" void kernel_launch(void* const* d_in, const int* in_sizes, int n_in,
                              void* d_out, int out_size, void* d_ws, size_t ws_size,
                              hipStream_t stream) {
  const void* x     = d_in[0];
  const void* coord = d_in[1];
  const void* W     = d_in[2];
  const void* a     = d_in[3];

  // ws: [512-float header: flag@0, MdstE @ uint 64 (stride 32)]
  //     [hT][WT][wa][fsrc][cpack]
  int*            flag  = (int*)d_ws;
  unsigned*       MdstE = (unsigned*)d_ws + 64;
  unsigned short* hT    = (unsigned short*)((float*)d_ws + 512);
  unsigned short* WT    = hT + (size_t)NROWS * FOUT_;
  float*          wa    = (float*)(WT + 128 * 256);
  float*          fsrc  = wa + 512;
  float4*         cpack = (float4*)(fsrc + NROWS);   // 16B-aligned offset

  k_prep<<<129, 256, 0, stream>>>(x, W, a, WT, wa, flag, MdstE);
  k_h   <<<NROWS / 32, 256, 0, stream>>>(x, coord, WT, wa, flag, hT, fsrc, cpack, MdstE);
  k_attn<<<B_ * (N_ / 64), 512, 0, stream>>>(hT, cpack, fsrc, MdstE, flag, d_out);
}

// Round 4
// 137.232 us; speedup vs baseline: 1.0182x; 1.0182x over previous
//
#include <hip/hip_runtime.h>
#include <hip/hip_bf16.h>

#define B_    8
#define N_    2048
#define FIN_  256
#define FOUT_ 128
#define NROWS (B_*N_)

typedef __attribute__((ext_vector_type(8))) short short8;
typedef __attribute__((ext_vector_type(4))) float f32x4;

__device__ __forceinline__ float bf2f(unsigned short u) {
  return __uint_as_float(((unsigned int)u) << 16);
}
__device__ __forceinline__ unsigned short f2bf(float f) {
  unsigned int u = __float_as_uint(f);
  u += 0x7FFFu + ((u >> 16) & 1u);   // RNE
  return (unsigned short)(u >> 16);
}
__device__ __forceinline__ float ldin(const void* p, size_t idx, int isbf) {
  if (isbf) return bf2f(((const unsigned short*)p)[idx]);
  return ((const float*)p)[idx];
}
__device__ __forceinline__ unsigned pk2bf(float a, float b) {
  return (unsigned)f2bf(a) | ((unsigned)f2bf(b) << 16);   // low = a (RNE)
}
// native exp2 (single v_exp_f32); fallback keeps exact same math via e^(x*ln2)
__device__ __forceinline__ float ex2(float x) {
#if __has_builtin(__builtin_amdgcn_exp2f)
  return __builtin_amdgcn_exp2f(x);
#else
  return __expf(x * 0.69314718056f);
#endif
}
// monotone float<->uint encoding for atomicMax float-max (all finite enc > 0)
__device__ __forceinline__ unsigned encf(float f) {
  unsigned u = __float_as_uint(f);
  return (u & 0x80000000u) ? ~u : (u | 0x80000000u);
}
__device__ __forceinline__ float decf(unsigned k) {
  return (k & 0x80000000u) ? __uint_as_float(k ^ 0x80000000u) : __uint_as_float(~k);
}
// per-block dtype self-detect (deterministic across blocks)
__device__ __forceinline__ int detect_bf(const void* x, int* cnt) {
  const unsigned short* u = (const unsigned short*)x;
  int c = 0;
  for (int i = threadIdx.x; i < 8192; i += 256) {
    unsigned short v = u[i];
    int e = (v >> 7) & 0xFF;
    if ((e >= 110 && e <= 145) || (v & 0x7FFF) == 0) c++;
  }
  cnt[threadIdx.x] = c;
  __syncthreads();
  for (int s = 128; s > 0; s >>= 1) {
    if (threadIdx.x < s) cnt[threadIdx.x] += cnt[threadIdx.x + s];
    __syncthreads();
  }
  return cnt[0] > 7373;   // 0.9 * 8192
}

// ---------- kernel 0: self-detect; blocks 0..127: WT; block 128: wa, flag,
//            MdstE init ----------
__global__ __launch_bounds__(256)
void k_prep(const void* __restrict__ x, const void* __restrict__ W,
            const void* __restrict__ a,
            unsigned short* __restrict__ WT, float* __restrict__ wa,
            int* __restrict__ flag, unsigned* __restrict__ MdstE) {
  __shared__ int cnt[256];
  const int isbf = detect_bf(x, cnt);
  if (blockIdx.x < 128) {
    int f = blockIdx.x, k = threadIdx.x;
    WT[f * 256 + k] = f2bf(ldin(W, (size_t)k * 128 + f, isbf));
  } else {
    __shared__ float as_s[256];
    int k = threadIdx.x;
    as_s[k] = ldin(a, k, isbf);
    __syncthreads();
    float s = 0.f, d = 0.f;
    for (int f = 0; f < 128; f++) {
      float w = ldin(W, (size_t)k * 128 + f, isbf);
      s += w * as_s[f];
      d += w * as_s[128 + f];
    }
    wa[k] = s;
    wa[256 + k] = d;
    if (k == 0) *flag = isbf;
    if (k < 8) MdstE[k * 32] = 0u;     // 0 < enc(f) for all finite f
  }
}

// ---------- kernel 1: h = x@W bf16 MFMA -> hT; fused fsrc/fdst = x@wa;
//            fused per-batch fdst max; cpack = (cx,cy,cz, fdst*log2e).
// hT 16B-half XOR swizzle on bit2 of f (phys_half = logical_half ^
// ((f>>2)&1)); k_attn reads with the matching hsel XOR. ----------
__global__ __launch_bounds__(256)
void k_h(const void* __restrict__ x, const void* __restrict__ coord,
         const unsigned short* __restrict__ WT,
         const float* __restrict__ wa, const int* __restrict__ flag,
         unsigned short* __restrict__ hT, float* __restrict__ fsrc,
         float4* __restrict__ cpack, unsigned* __restrict__ MdstE) {
  __shared__ __align__(16) unsigned short xs[32][264];
  __shared__ float wa_s[512];
  __shared__ float mxs[8];
  const int isbf = *flag;
  const int t    = threadIdx.x;
  const int row0 = blockIdx.x * 32;

  wa_s[t] = wa[t];
  wa_s[256 + t] = wa[256 + t];
  __syncthreads();

  const int c = t & 31;
  float sp[4], dp[4];
  if (isbf) {
    const unsigned short* xu = (const unsigned short*)x;
#pragma unroll
    for (int u = 0; u < 4; u++) {
      int r = u * 8 + (t >> 5);
      short8 sh = *(const short8*)&xu[(size_t)(row0 + r) * FIN_ + c * 8];
      *(short8*)&xs[r][c * 8] = sh;
      float s = 0.f, d = 0.f;
#pragma unroll
      for (int e = 0; e < 8; e++) {
        float xv = bf2f((unsigned short)sh[e]);
        s += xv * wa_s[c * 8 + e];
        d += xv * wa_s[256 + c * 8 + e];
      }
      sp[u] = s; dp[u] = d;
    }
  } else {
    const float* xf = (const float*)x;
#pragma unroll
    for (int u = 0; u < 4; u++) {
      int r = u * 8 + (t >> 5);
      float4 v0 = *(const float4*)&xf[(size_t)(row0 + r) * FIN_ + c * 8];
      float4 v1 = *(const float4*)&xf[(size_t)(row0 + r) * FIN_ + c * 8 + 4];
      float vv[8] = {v0.x, v0.y, v0.z, v0.w, v1.x, v1.y, v1.z, v1.w};
      short8 sh;
      float s = 0.f, d = 0.f;
#pragma unroll
      for (int e = 0; e < 8; e++) {
        sh[e] = (short)f2bf(vv[e]);
        s += vv[e] * wa_s[c * 8 + e];
        d += vv[e] * wa_s[256 + c * 8 + e];
      }
      *(short8*)&xs[r][c * 8] = sh;
      sp[u] = s; dp[u] = d;
    }
  }
#pragma unroll
  for (int off = 16; off >= 1; off >>= 1) {
#pragma unroll
    for (int u = 0; u < 4; u++) {
      sp[u] += __shfl_xor(sp[u], off, 64);
      dp[u] += __shfl_xor(dp[u], off, 64);
    }
  }
  if (c == 0) {
    float lm = -1e30f;
#pragma unroll
    for (int u = 0; u < 4; u++) {
      int r = u * 8 + (t >> 5);
      size_t rg = (size_t)(row0 + r);
      fsrc[rg] = sp[u];
      cpack[rg] = make_float4(ldin(coord, rg * 3 + 0, isbf),
                              ldin(coord, rg * 3 + 1, isbf),
                              ldin(coord, rg * 3 + 2, isbf),
                              dp[u] * 1.44269504f);     // fdst pre-scaled by log2e
      lm = fmaxf(lm, dp[u]);
    }
    mxs[t >> 5] = lm;
  }
  __syncthreads();
  if (t == 0) {
    float m8 = mxs[0];
#pragma unroll
    for (int i = 1; i < 8; i++) m8 = fmaxf(m8, mxs[i]);
    atomicMax(&MdstE[(row0 >> 11) * 32], encf(m8));   // 64 atomics/line, padded
  }

  const int lane = t & 63, w = t >> 6;
  const int m = lane & 15, quad = lane >> 4;
  const int slab = w >> 1, fh = w & 1;

  f32x4 acc[4];
#pragma unroll
  for (int i = 0; i < 4; i++) acc[i] = (f32x4){0.f, 0.f, 0.f, 0.f};

#pragma unroll
  for (int ks = 0; ks < 8; ks++) {
    short8 ah = *(const short8*)&xs[slab * 16 + m][ks * 32 + quad * 8];
#pragma unroll
    for (int ft = 0; ft < 4; ft++) {
      int f = fh * 64 + ft * 16 + m;
      short8 bh = *(const short8*)&WT[(size_t)f * 256 + ks * 32 + quad * 8];
      acc[ft] = __builtin_amdgcn_mfma_f32_16x16x32_bf16(ah, bh, acc[ft], 0, 0, 0);
    }
  }

  size_t n0 = (size_t)blockIdx.x * 2 + slab;
  unsigned short* hblk = hT + n0 * (FOUT_ * 16);
#pragma unroll
  for (int ft = 0; ft < 4; ft++) {
    int f = fh * 64 + ft * 16 + m;
    int jo = (quad * 4) ^ (((f >> 2) & 1) << 3);   // bank-swizzled 16B half
    *(uint2*)&hblk[f * 16 + jo] = make_uint2(
        pk2bf(acc[ft][0], acc[ft][1]), pk2bf(acc[ft][2], acc[ft][3]));
  }
}

// ---------- kernel 2 (r21): r20 pipeline, 1024 threads = 4 waves/SIMD ------
// r0/r18/r20 (three different structures) all sit at 43-47 us: VALU cut and
// VMEM cut both ~neutral => the shared constraint is unfilled latency slots.
// r20 ran 512 thr + 103 KB LDS = 1 block/CU = 2 waves/SIMD -- too few to
// cover ds_read (~120cy), v_exp, and VMEM prefetch latencies (measured time
// ~2.2x the LDS-array floor of ~19 us). r21 keeps the IDENTICAL pipeline,
// buffers, barriers, and swizzles but runs 1024 thr (16 waves = 4/SIMD),
// halving per-thread work: 8 logit pairs, 2 staging uint4s, per-wave MFMA =
// 1 qtile x 2 ftiles (4 q-groups x 4 f-groups). LDS instrs/tile unchanged
// (~368: B 128 + phiA 64 + cjs 128 + stage 32 + phiW 16) -- pure TLP gain.
__global__ __launch_bounds__(1024, 4)
void k_attn(const unsigned short* __restrict__ hT, const float4* __restrict__ cpack,
            const float* __restrict__ fsrc, const unsigned* __restrict__ MdstE,
            const int* __restrict__ flag, void* __restrict__ out) {
  const int isbf = *flag;
  const int tid = threadIdx.x;
  const int b   = blockIdx.x >> 5;
  const int q0  = (blockIdx.x & 31) * 64;

  __shared__ __align__(16) uint4 ldsBu[2][2048];            // 64 KB B panels
  __shared__ __align__(16) unsigned short phi[2][64][136];  // 34 KB
  __shared__ __align__(16) float4 cjs[2][144];              // 4.5 KB (padded)
  __shared__ float denomS[64];

  const int qA   = tid >> 4;              // 0..63: logit q row
  const int jseg = tid & 15;              // 8 j's: jseg*8 + 0..7
  const size_t qglb = (size_t)b * N_ + q0 + qA;
  const float4 cq  = cpack[qglb];
  const float  fsq = fsrc[qglb];
  const float  fsqL = fsq * 1.44269504f;
  const float  mBqL = -fmaxf(0.f, fsq + decf(MdstE[b * 32])) * 1.44269504f;

  const int lane = tid & 63, w = tid >> 6;
  const int m = lane & 15, quad = lane >> 4;
  const int qg = w & 3, fg = w >> 2;      // 4 q-groups x 4 f-groups
  const int hsel = (quad & 1) ^ ((m >> 2) & 1);   // undo producer swizzle

  f32x4 acc[2], accD;
  acc[0] = (f32x4){0.f, 0.f, 0.f, 0.f};
  acc[1] = (f32x4){0.f, 0.f, 0.f, 0.f};
  accD   = (f32x4){0.f, 0.f, 0.f, 0.f};
  const short8 bones = {(short)0x3F80, (short)0x3F80, (short)0x3F80, (short)0x3F80,
                        (short)0x3F80, (short)0x3F80, (short)0x3F80, (short)0x3F80};

  const unsigned short* hTb = hT + (size_t)b * (N_ * FOUT_);
  const uint4* gB = (const uint4*)hTb;            // 2048 uint4 per 128-j tile
  const float4* cpb = cpack + (size_t)b * N_;

  // logits for tile tt -> 4 packed bf16 pairs (8 j's)
  auto logits = [&](int tt, unsigned* pk) {
    const float4* cb = cjs[tt & 1];
#pragma unroll
    for (int jp = 0; jp < 4; jp++) {
      const int j0 = jseg * 8 + 2 * jp;
      const int ix = j0 + (j0 >> 3);
      const float4 cj0 = cb[ix];
      const float4 cj1 = cb[ix + 1];
      float dx0 = cq.x - cj0.x, dy0 = cq.y - cj0.y, dz0 = cq.z - cj0.z;
      float dx1 = cq.x - cj1.x, dy1 = cq.y - cj1.y, dz1 = cq.z - cj1.z;
      float d20 = fmaf(dz0, dz0, fmaf(dy0, dy0, dx0 * dx0));
      float d21 = fmaf(dz1, dz1, fmaf(dy1, dy1, dx1 * dx1));
      float loc0 = ex2(-0.14426950408f * d20);       // = exp(-0.1*d2)
      float loc1 = ex2(-0.14426950408f * d21);
      float xL0 = fsqL + cj0.w, xL1 = fsqL + cj1.w;  // (fsq+fdst)*log2e
      float eL0 = fmaxf(xL0, 0.2f * xL0);            // leaky, scale-invariant
      float eL1 = fmaxf(xL1, 0.2f * xL1);
      float p0 = ex2(fmaf(eL0, loc0, mBqL));         // = exp(e*loc - Bq)
      float p1 = ex2(fmaf(eL1, loc1, mBqL));
      p0 = (d20 < 46.0517f) ? p0 : 0.f;
      p1 = (d21 < 46.0517f) ? p1 : 0.f;
      unsigned r;
      asm("v_cvt_pk_bf16_f32 %0, %1, %2" : "=v"(r) : "v"(p0), "v"(p1));
      pk[jp] = r;
    }
  };

  auto store_phi = [&](int tt, const unsigned* pk) {
    *(uint4*)&phi[tt & 1][qA][jseg * 8] =
        make_uint4(pk[0], pk[1], pk[2], pk[3]);
  };

  auto mfma_tile = [&](int tb) {
    const unsigned short* pb = &phi[tb][qg * 16 + m][0];
    const unsigned short* bb = (const unsigned short*)ldsBu[tb];
#pragma unroll
    for (int ks = 0; ks < 4; ks++) {
      short8 ah = *(const short8*)&pb[ks * 32 + quad * 8];
      if (fg == 0)
        accD = __builtin_amdgcn_mfma_f32_16x16x32_bf16(ah, bones, accD, 0, 0, 0);
#pragma unroll
      for (int ft = 0; ft < 2; ft++) {
        const int f = fg * 32 + ft * 16 + m;
        const short8 bh = *(const short8*)
            &bb[(ks * 2 + (quad >> 1)) * 2048 + f * 16 + hsel * 8];
        acc[ft] = __builtin_amdgcn_mfma_f32_16x16x32_bf16(ah, bh, acc[ft], 0, 0, 0);
      }
    }
  };

  // ---- prologue: coords tiles 0,1; B panel 0 (reg-staged); logits(0) ----
  if (tid < 256) {
    const int tile = tid >> 7, j = tid & 127;
    cjs[tile][j + (j >> 3)] = cpb[tid];
  }
  {
    uint4 pv[2];
#pragma unroll
    for (int k = 0; k < 2; k++) pv[k] = gB[k * 1024 + tid];
#pragma unroll
    for (int k = 0; k < 2; k++) ldsBu[0][k * 1024 + tid] = pv[k];
  }
  __syncthreads();                         // cjs[0,1] + ldsB[0] ready
  {
    unsigned pk0[4];
    logits(0, pk0);
    store_phi(0, pk0);
  }
  __syncthreads();                         // phi[0] ready

  // ---- main loop: one barrier per 128-j tile ----
  const int jr = tid & 127;
  for (int t = 0; t < 16; t++) {
    // 1. issue next-tile loads (latency hides under logits+MFMA below)
    uint4 bv[2];
    if (t < 15) {
#pragma unroll
      for (int k = 0; k < 2; k++)
        bv[k] = gB[(size_t)(t + 1) * 2048 + k * 1024 + tid];
    }
    float4 cg;
    if (t < 14 && tid < 128) cg = cpb[(t + 2) * 128 + jr];

    // 2. logits for tile t+1 (VALU-heavy; overlaps loads + MFMA)
    unsigned pk[4];
    if (t < 15) logits(t + 1, pk);         // reads cjs[(t+1)&1]

    // 3. MFMA for tile t
    mfma_tile(t & 1);                      // reads phi[t&1], ldsB[t&1]

    // 4. publish tile t+1 state (writes go to the OTHER buffers; prior
    //    reads of those buffers were fenced by the barrier at end of t-1)
    if (t < 15) {
#pragma unroll
      for (int k = 0; k < 2; k++)
        ldsBu[(t + 1) & 1][k * 1024 + tid] = bv[k];
      store_phi(t + 1, pk);                // -> phi[(t+1)&1]
    }
    if (t < 14 && tid < 128) cjs[t & 1][jr + (jr >> 3)] = cg;  // tile t+2
    __syncthreads();
  }

  // ---- denominator share, normalize, elu, store ----
  if (fg == 0 && m == 0) {
#pragma unroll
    for (int r = 0; r < 4; r++) denomS[qg * 16 + quad * 4 + r] = accD[r];
  }
  __syncthreads();
#pragma unroll
  for (int ft = 0; ft < 2; ft++) {
    const int f = fg * 32 + ft * 16 + m;
#pragma unroll
    for (int r = 0; r < 4; r++) {
      const int q = qg * 16 + quad * 4 + r;
      float v = acc[ft][r] / fmaxf(denomS[q], 1e-30f);
      v = (v > 0.f) ? v : (__expf(v) - 1.0f);
      size_t oidx = ((size_t)(b * N_ + q0 + q)) * FOUT_ + f;
      if (isbf) ((unsigned short*)out)[oidx] = f2bf(v);
      else      ((float*)out)[oidx] = v;
    }
  }
}

extern "C" void kernel_launch(void* const* d_in, const int* in_sizes, int n_in,
                              void* d_out, int out_size, void* d_ws, size_t ws_size,
                              hipStream_t stream) {
  const void* x     = d_in[0];
  const void* coord = d_in[1];
  const void* W     = d_in[2];
  const void* a     = d_in[3];

  // ws: [512-float header: flag@0, MdstE @ uint 64 (stride 32)]
  //     [hT][WT][wa][fsrc][cpack]
  int*            flag  = (int*)d_ws;
  unsigned*       MdstE = (unsigned*)d_ws + 64;
  unsigned short* hT    = (unsigned short*)((float*)d_ws + 512);
  unsigned short* WT    = hT + (size_t)NROWS * FOUT_;
  float*          wa    = (float*)(WT + 128 * 256);
  float*          fsrc  = wa + 512;
  float4*         cpack = (float4*)(fsrc + NROWS);   // 16B-aligned offset

  k_prep<<<129, 256, 0, stream>>>(x, W, a, WT, wa, flag, MdstE);
  k_h   <<<NROWS / 32, 256, 0, stream>>>(x, coord, WT, wa, flag, hT, fsrc, cpack, MdstE);
  k_attn<<<B_ * (N_ / 64), 1024, 0, stream>>>(hT, cpack, fsrc, MdstE, flag, d_out);
}

// Round 9
// 132.629 us; speedup vs baseline: 1.0535x; 1.0347x over previous
//
#include <hip/hip_runtime.h>
#include <hip/hip_bf16.h>

#define B_    8
#define N_    2048
#define FIN_  256
#define FOUT_ 128
#define NROWS (B_*N_)

typedef __attribute__((ext_vector_type(8))) short short8;
typedef __attribute__((ext_vector_type(4))) float f32x4;

__device__ __forceinline__ float bf2f(unsigned short u) {
  return __uint_as_float(((unsigned int)u) << 16);
}
__device__ __forceinline__ unsigned short f2bf(float f) {
  unsigned int u = __float_as_uint(f);
  u += 0x7FFFu + ((u >> 16) & 1u);   // RNE
  return (unsigned short)(u >> 16);
}
__device__ __forceinline__ float ldin(const void* p, size_t idx, int isbf) {
  if (isbf) return bf2f(((const unsigned short*)p)[idx]);
  return ((const float*)p)[idx];
}
__device__ __forceinline__ unsigned pk2bf(float a, float b) {
  return (unsigned)f2bf(a) | ((unsigned)f2bf(b) << 16);   // low = a (RNE)
}
// native exp2 (single v_exp_f32); fallback keeps exact same math via e^(x*ln2)
__device__ __forceinline__ float ex2(float x) {
#if __has_builtin(__builtin_amdgcn_exp2f)
  return __builtin_amdgcn_exp2f(x);
#else
  return __expf(x * 0.69314718056f);
#endif
}
// monotone float<->uint encoding for atomicMax float-max (all finite enc > 0)
__device__ __forceinline__ unsigned encf(float f) {
  unsigned u = __float_as_uint(f);
  return (u & 0x80000000u) ? ~u : (u | 0x80000000u);
}
__device__ __forceinline__ float decf(unsigned k) {
  return (k & 0x80000000u) ? __uint_as_float(k ^ 0x80000000u) : __uint_as_float(~k);
}
// per-block dtype self-detect (deterministic across blocks)
__device__ __forceinline__ int detect_bf(const void* x, int* cnt) {
  const unsigned short* u = (const unsigned short*)x;
  int c = 0;
  for (int i = threadIdx.x; i < 8192; i += 256) {
    unsigned short v = u[i];
    int e = (v >> 7) & 0xFF;
    if ((e >= 110 && e <= 145) || (v & 0x7FFF) == 0) c++;
  }
  cnt[threadIdx.x] = c;
  __syncthreads();
  for (int s = 128; s > 0; s >>= 1) {
    if (threadIdx.x < s) cnt[threadIdx.x] += cnt[threadIdx.x + s];
    __syncthreads();
  }
  return cnt[0] > 7373;   // 0.9 * 8192
}

// ---------- kernel 0: self-detect; blocks 0..127: WT; block 128: wa, flag,
//            MdstE init ----------
__global__ __launch_bounds__(256)
void k_prep(const void* __restrict__ x, const void* __restrict__ W,
            const void* __restrict__ a,
            unsigned short* __restrict__ WT, float* __restrict__ wa,
            int* __restrict__ flag, unsigned* __restrict__ MdstE) {
  __shared__ int cnt[256];
  const int isbf = detect_bf(x, cnt);
  if (blockIdx.x < 128) {
    int f = blockIdx.x, k = threadIdx.x;
    WT[f * 256 + k] = f2bf(ldin(W, (size_t)k * 128 + f, isbf));
  } else {
    __shared__ float as_s[256];
    int k = threadIdx.x;
    as_s[k] = ldin(a, k, isbf);
    __syncthreads();
    float s = 0.f, d = 0.f;
    for (int f = 0; f < 128; f++) {
      float w = ldin(W, (size_t)k * 128 + f, isbf);
      s += w * as_s[f];
      d += w * as_s[128 + f];
    }
    wa[k] = s;
    wa[256 + k] = d;
    if (k == 0) *flag = isbf;
    if (k < 8) MdstE[k * 32] = 0u;     // 0 < enc(f) for all finite f
  }
}

// ---------- kernel 1: h = x@W bf16 MFMA -> hT; fused fsrc/fdst = x@wa;
//            fused per-batch fdst max; cpack = (cx,cy,cz, fdst*log2e).
// hT 16B-half XOR swizzle on bit2 of f (phys_half = logical_half ^
// ((f>>2)&1)); k_attn reads with the matching hsel XOR. ----------
__global__ __launch_bounds__(256)
void k_h(const void* __restrict__ x, const void* __restrict__ coord,
         const unsigned short* __restrict__ WT,
         const float* __restrict__ wa, const int* __restrict__ flag,
         unsigned short* __restrict__ hT, float* __restrict__ fsrc,
         float4* __restrict__ cpack, unsigned* __restrict__ MdstE) {
  __shared__ __align__(16) unsigned short xs[32][264];
  __shared__ float wa_s[512];
  __shared__ float mxs[8];
  const int isbf = *flag;
  const int t    = threadIdx.x;
  const int row0 = blockIdx.x * 32;

  wa_s[t] = wa[t];
  wa_s[256 + t] = wa[256 + t];
  __syncthreads();

  const int c = t & 31;
  float sp[4], dp[4];
  if (isbf) {
    const unsigned short* xu = (const unsigned short*)x;
#pragma unroll
    for (int u = 0; u < 4; u++) {
      int r = u * 8 + (t >> 5);
      short8 sh = *(const short8*)&xu[(size_t)(row0 + r) * FIN_ + c * 8];
      *(short8*)&xs[r][c * 8] = sh;
      float s = 0.f, d = 0.f;
#pragma unroll
      for (int e = 0; e < 8; e++) {
        float xv = bf2f((unsigned short)sh[e]);
        s += xv * wa_s[c * 8 + e];
        d += xv * wa_s[256 + c * 8 + e];
      }
      sp[u] = s; dp[u] = d;
    }
  } else {
    const float* xf = (const float*)x;
#pragma unroll
    for (int u = 0; u < 4; u++) {
      int r = u * 8 + (t >> 5);
      float4 v0 = *(const float4*)&xf[(size_t)(row0 + r) * FIN_ + c * 8];
      float4 v1 = *(const float4*)&xf[(size_t)(row0 + r) * FIN_ + c * 8 + 4];
      float vv[8] = {v0.x, v0.y, v0.z, v0.w, v1.x, v1.y, v1.z, v1.w};
      short8 sh;
      float s = 0.f, d = 0.f;
#pragma unroll
      for (int e = 0; e < 8; e++) {
        sh[e] = (short)f2bf(vv[e]);
        s += vv[e] * wa_s[c * 8 + e];
        d += vv[e] * wa_s[256 + c * 8 + e];
      }
      *(short8*)&xs[r][c * 8] = sh;
      sp[u] = s; dp[u] = d;
    }
  }
#pragma unroll
  for (int off = 16; off >= 1; off >>= 1) {
#pragma unroll
    for (int u = 0; u < 4; u++) {
      sp[u] += __shfl_xor(sp[u], off, 64);
      dp[u] += __shfl_xor(dp[u], off, 64);
    }
  }
  if (c == 0) {
    float lm = -1e30f;
#pragma unroll
    for (int u = 0; u < 4; u++) {
      int r = u * 8 + (t >> 5);
      size_t rg = (size_t)(row0 + r);
      fsrc[rg] = sp[u];
      cpack[rg] = make_float4(ldin(coord, rg * 3 + 0, isbf),
                              ldin(coord, rg * 3 + 1, isbf),
                              ldin(coord, rg * 3 + 2, isbf),
                              dp[u] * 1.44269504f);     // fdst pre-scaled by log2e
      lm = fmaxf(lm, dp[u]);
    }
    mxs[t >> 5] = lm;
  }
  __syncthreads();
  if (t == 0) {
    float m8 = mxs[0];
#pragma unroll
    for (int i = 1; i < 8; i++) m8 = fmaxf(m8, mxs[i]);
    atomicMax(&MdstE[(row0 >> 11) * 32], encf(m8));   // 64 atomics/line, padded
  }

  const int lane = t & 63, w = t >> 6;
  const int m = lane & 15, quad = lane >> 4;
  const int slab = w >> 1, fh = w & 1;

  f32x4 acc[4];
#pragma unroll
  for (int i = 0; i < 4; i++) acc[i] = (f32x4){0.f, 0.f, 0.f, 0.f};

#pragma unroll
  for (int ks = 0; ks < 8; ks++) {
    short8 ah = *(const short8*)&xs[slab * 16 + m][ks * 32 + quad * 8];
#pragma unroll
    for (int ft = 0; ft < 4; ft++) {
      int f = fh * 64 + ft * 16 + m;
      short8 bh = *(const short8*)&WT[(size_t)f * 256 + ks * 32 + quad * 8];
      acc[ft] = __builtin_amdgcn_mfma_f32_16x16x32_bf16(ah, bh, acc[ft], 0, 0, 0);
    }
  }

  size_t n0 = (size_t)blockIdx.x * 2 + slab;
  unsigned short* hblk = hT + n0 * (FOUT_ * 16);
#pragma unroll
  for (int ft = 0; ft < 4; ft++) {
    int f = fh * 64 + ft * 16 + m;
    int jo = (quad * 4) ^ (((f >> 2) & 1) << 3);   // bank-swizzled 16B half
    *(uint2*)&hblk[f * 16 + jo] = make_uint2(
        pk2bf(acc[ft][0], acc[ft][1]), pk2bf(acc[ft][2], acc[ft][3]));
  }
}

// ---------- kernel 2 (r26): r21 logits + js-split MFMA -------------------
// Bisection (r25) convicted the 2q x 4j logits remap (r21+remap-only failed
// 0.39); it is ABANDONED. r22/r24's failures are attributed to it, so the
// js-split MFMA (untested alone) gets its clean shot here:
//   - logits/store_phi/roles: r21 VERBATIM (qA=tid>>4, jseg=tid&15, 8 j's,
//     one uint4 store). Only addition: ds += the 8 bf16-rounded p values
//     (extracted from the same pk words the MFMA consumes).
//   - MFMA: 16 waves = 4 fg x 4 js (K-quarter). r21-verified expressions
//     with (qg,ks)->(qt,js): A j = js*32+quad*8+e; B j identical (re-derived
//     through the hT swizzle). Per wave/tile: 4 A + 2 B reads (was 4+8).
//   - denominator: bones-MFMA removed (-16 MFMA/tile); end-of-kernel 16-lane
//     __shfl_xor reduce of ds -> denomS (order-only f32 delta, ~1e-6 rel).
//   - js-partial merge once at the end in the dead ldsB (bijective slots,
//     3 non-divergent barriers, exactly 64 KB).
// LDS wave-instrs/tile ~368 -> ~272; MFMA/tile 48 -> 32.
__global__ __launch_bounds__(1024, 4)
void k_attn(const unsigned short* __restrict__ hT, const float4* __restrict__ cpack,
            const float* __restrict__ fsrc, const unsigned* __restrict__ MdstE,
            const int* __restrict__ flag, void* __restrict__ out) {
  const int isbf = *flag;
  const int tid = threadIdx.x;
  const int b   = blockIdx.x >> 5;
  const int q0  = (blockIdx.x & 31) * 64;

  __shared__ __align__(16) uint4 ldsBu[2][2048];            // 64 KB B panels
  __shared__ __align__(16) unsigned short phi[2][64][136];  // 34 KB
  __shared__ __align__(16) float4 cjs[2][144];              // 4.5 KB (padded)
  __shared__ float denomS[64];

  // ---- logit roles (r21 verbatim) ----
  const int qA   = tid >> 4;              // 0..63: logit q row
  const int jseg = tid & 15;              // 8 j's: jseg*8 + 0..7
  const size_t qglb = (size_t)b * N_ + q0 + qA;
  const float4 cq  = cpack[qglb];
  const float  fsq = fsrc[qglb];
  const float  fsqL = fsq * 1.44269504f;
  const float  mBqL = -fmaxf(0.f, fsq + decf(MdstE[b * 32])) * 1.44269504f;
  float ds = 0.f;                         // f32 sum of this thread's bf16 p's

  // ---- mfma roles: 16 waves = 4 fg x 4 js (K-quarter) ----
  const int lane = tid & 63, w = tid >> 6;
  const int m = lane & 15, quad = lane >> 4;
  const int fg = w & 3, js = w >> 2;
  const int hsel = (quad & 1) ^ ((m >> 2) & 1);   // undo producer swizzle

  f32x4 acc[4][2];                        // [q-tile][f-subtile]
#pragma unroll
  for (int i = 0; i < 4; i++)
#pragma unroll
    for (int j = 0; j < 2; j++) acc[i][j] = (f32x4){0.f, 0.f, 0.f, 0.f};

  const unsigned short* hTb = hT + (size_t)b * (N_ * FOUT_);
  const uint4* gB = (const uint4*)hTb;            // 2048 uint4 per 128-j tile
  const float4* cpb = cpack + (size_t)b * N_;

  // logits for tile tt -> 4 packed bf16 pairs (8 j's) + denom accumulation
  auto logits = [&](int tt, unsigned* pk) {
    const float4* cb = cjs[tt & 1];
#pragma unroll
    for (int jp = 0; jp < 4; jp++) {
      const int j0 = jseg * 8 + 2 * jp;
      const int ix = j0 + (j0 >> 3);
      const float4 cj0 = cb[ix];
      const float4 cj1 = cb[ix + 1];
      float dx0 = cq.x - cj0.x, dy0 = cq.y - cj0.y, dz0 = cq.z - cj0.z;
      float dx1 = cq.x - cj1.x, dy1 = cq.y - cj1.y, dz1 = cq.z - cj1.z;
      float d20 = fmaf(dz0, dz0, fmaf(dy0, dy0, dx0 * dx0));
      float d21 = fmaf(dz1, dz1, fmaf(dy1, dy1, dx1 * dx1));
      float loc0 = ex2(-0.14426950408f * d20);       // = exp(-0.1*d2)
      float loc1 = ex2(-0.14426950408f * d21);
      float xL0 = fsqL + cj0.w, xL1 = fsqL + cj1.w;  // (fsq+fdst)*log2e
      float eL0 = fmaxf(xL0, 0.2f * xL0);            // leaky, scale-invariant
      float eL1 = fmaxf(xL1, 0.2f * xL1);
      float p0 = ex2(fmaf(eL0, loc0, mBqL));         // = exp(e*loc - Bq)
      float p1 = ex2(fmaf(eL1, loc1, mBqL));
      p0 = (d20 < 46.0517f) ? p0 : 0.f;
      p1 = (d21 < 46.0517f) ? p1 : 0.f;
      unsigned r;
      asm("v_cvt_pk_bf16_f32 %0, %1, %2" : "=v"(r) : "v"(p0), "v"(p1));
      pk[jp] = r;
    }
    // denominator: sum the bf16-ROUNDED p's (exactly what the MFMA consumes)
#pragma unroll
    for (int jp = 0; jp < 4; jp++)
      ds += bf2f((unsigned short)(pk[jp] & 0xFFFF)) +
            bf2f((unsigned short)(pk[jp] >> 16));
  };

  auto store_phi = [&](int tt, const unsigned* pk) {
    *(uint4*)&phi[tt & 1][qA][jseg * 8] =
        make_uint4(pk[0], pk[1], pk[2], pk[3]);
  };

  // js-split MFMA: wave (fg, js) covers all 4 q-tiles x 32 f at K-slice js
  auto mfma_tile = [&](int tb) {
    const unsigned short* bb = (const unsigned short*)ldsBu[tb];
    const int f0 = fg * 32 + m;
    const short8 bh0 = *(const short8*)
        &bb[(js * 2 + (quad >> 1)) * 2048 + f0 * 16 + hsel * 8];
    const short8 bh1 = *(const short8*)
        &bb[(js * 2 + (quad >> 1)) * 2048 + (f0 + 16) * 16 + hsel * 8];
#pragma unroll
    for (int qt = 0; qt < 4; qt++) {
      short8 ah = *(const short8*)&phi[tb][qt * 16 + m][js * 32 + quad * 8];
      acc[qt][0] = __builtin_amdgcn_mfma_f32_16x16x32_bf16(ah, bh0, acc[qt][0], 0, 0, 0);
      acc[qt][1] = __builtin_amdgcn_mfma_f32_16x16x32_bf16(ah, bh1, acc[qt][1], 0, 0, 0);
    }
  };

  // ---- prologue: coords tiles 0,1; B panel 0 (reg-staged); logits(0) ----
  if (tid < 256) {
    const int tile = tid >> 7, j = tid & 127;
    cjs[tile][j + (j >> 3)] = cpb[tid];
  }
  {
    uint4 pv[2];
#pragma unroll
    for (int k = 0; k < 2; k++) pv[k] = gB[k * 1024 + tid];
#pragma unroll
    for (int k = 0; k < 2; k++) ldsBu[0][k * 1024 + tid] = pv[k];
  }
  __syncthreads();                         // cjs[0,1] + ldsB[0] ready
  {
    unsigned pk0[4];
    logits(0, pk0);
    store_phi(0, pk0);
  }
  __syncthreads();                         // phi[0] ready

  // ---- main loop: one barrier per 128-j tile ----
  const int jr = tid & 127;
  for (int t = 0; t < 16; t++) {
    // 1. issue next-tile loads (latency hides under logits+MFMA below)
    uint4 bv[2];
    if (t < 15) {
#pragma unroll
      for (int k = 0; k < 2; k++)
        bv[k] = gB[(size_t)(t + 1) * 2048 + k * 1024 + tid];
    }
    float4 cg;
    if (t < 14 && tid < 128) cg = cpb[(t + 2) * 128 + jr];

    // 2. logits for tile t+1 (VALU-heavy; overlaps loads + MFMA)
    unsigned pk[4];
    if (t < 15) logits(t + 1, pk);         // reads cjs[(t+1)&1]

    // 3. MFMA for tile t
    mfma_tile(t & 1);                      // reads phi[t&1], ldsB[t&1]

    // 4. publish tile t+1 state (writes go to the OTHER buffers; prior
    //    reads of those buffers were fenced by the barrier at end of t-1)
    if (t < 15) {
#pragma unroll
      for (int k = 0; k < 2; k++)
        ldsBu[(t + 1) & 1][k * 1024 + tid] = bv[k];
      store_phi(t + 1, pk);                // -> phi[(t+1)&1]
    }
    if (t < 14 && tid < 128) cjs[t & 1][jr + (jr >> 3)] = cg;  // tile t+2
    __syncthreads();
  }

  // ---- denominator: 16-lane group reduce (threads sharing qA) ----
#pragma unroll
  for (int off = 1; off <= 8; off <<= 1) ds += __shfl_xor(ds, off, 64);
  if (jseg == 0) denomS[qA] = ds;          // read after the merge barriers

  // ---- js-partial acc merge: 2 rounds in the dead ldsB buffer ----
  f32x4* xv = (f32x4*)ldsBu;               // 4096 f32x4 = 64 KB
  auto writeSlot = [&](int slot) {
#pragma unroll
    for (int qt = 0; qt < 4; qt++)
#pragma unroll
      for (int ft = 0; ft < 2; ft++) {
        const int i = qt * 2 + ft;
        xv[slot * 512 + lane * 8 + (i ^ (lane & 7))] = acc[qt][ft];
      }
  };
  auto readSlot = [&](int slot) {
#pragma unroll
    for (int qt = 0; qt < 4; qt++)
#pragma unroll
      for (int ft = 0; ft < 2; ft++) {
        const int i = qt * 2 + ft;
        acc[qt][ft] += xv[slot * 512 + lane * 8 + (i ^ (lane & 7))];
      }
  };
  if (js & 1) writeSlot(fg * 2 + (js >> 1));     // js 1,3 -> slots 0..7
  __syncthreads();
  if (!(js & 1)) readSlot(fg * 2 + (js >> 1));   // js0 += js1; js2 += js3
  __syncthreads();
  if (js == 2) writeSlot(fg);                    // merged js2+3 -> slots 0..3
  __syncthreads();

  // ---- final merge + normalize + elu + store (js==0 waves) ----
  if (js == 0) {
    readSlot(fg);
#pragma unroll
    for (int ft = 0; ft < 2; ft++) {
      const int f = fg * 32 + ft * 16 + m;
#pragma unroll
      for (int qt = 0; qt < 4; qt++)
#pragma unroll
        for (int r = 0; r < 4; r++) {
          const int q = qt * 16 + quad * 4 + r;
          float v = acc[qt][ft][r] / fmaxf(denomS[q], 1e-30f);
          v = (v > 0.f) ? v : (__expf(v) - 1.0f);
          size_t oidx = ((size_t)(b * N_ + q0 + q)) * FOUT_ + f;
          if (isbf) ((unsigned short*)out)[oidx] = f2bf(v);
          else      ((float*)out)[oidx] = v;
        }
    }
  }
}

extern "C" void kernel_launch(void* const* d_in, const int* in_sizes, int n_in,
                              void* d_out, int out_size, void* d_ws, size_t ws_size,
                              hipStream_t stream) {
  const void* x     = d_in[0];
  const void* coord = d_in[1];
  const void* W     = d_in[2];
  const void* a     = d_in[3];

  // ws: [512-float header: flag@0, MdstE @ uint 64 (stride 32)]
  //     [hT][WT][wa][fsrc][cpack]
  int*            flag  = (int*)d_ws;
  unsigned*       MdstE = (unsigned*)d_ws + 64;
  unsigned short* hT    = (unsigned short*)((float*)d_ws + 512);
  unsigned short* WT    = hT + (size_t)NROWS * FOUT_;
  float*          wa    = (float*)(WT + 128 * 256);
  float*          fsrc  = wa + 512;
  float4*         cpack = (float4*)(fsrc + NROWS);   // 16B-aligned offset

  k_prep<<<129, 256, 0, stream>>>(x, W, a, WT, wa, flag, MdstE);
  k_h   <<<NROWS / 32, 256, 0, stream>>>(x, coord, WT, wa, flag, hT, fsrc, cpack, MdstE);
  k_attn<<<B_ * (N_ / 64), 1024, 0, stream>>>(hT, cpack, fsrc, MdstE, flag, d_out);
}